// Round 5
// baseline (1018.059 us; speedup 1.0000x reference)
//
#include <hip/hip_runtime.h>
#include <cstdint>
#include <cstddef>

// Problem constants
#define B_   2
#define S_   2048
#define D_   2048
#define H_   8
#define HD_  256
#define M_   (B_ * S_)        // 4096 rows
#define NQ_  (H_ * HD_)       // 2048
#define NKV_ 256

typedef unsigned short u16;
typedef __attribute__((ext_vector_type(8))) short short8v;   // 8 bf16 (4 VGPRs)
typedef __attribute__((ext_vector_type(4))) float f32x4;     // MFMA acc frag

__device__ __forceinline__ u16 f2bf_rn(float x) {
    unsigned int u = __float_as_uint(x);
    unsigned int r = u + 0x7FFFu + ((u >> 16) & 1u);
    return (u16)(r >> 16);
}
__device__ __forceinline__ float bf2f(u16 h) {
    return __uint_as_float(((unsigned int)h) << 16);
}

// async global->LDS, 16B per lane, LDS dest = wave-uniform base + lane*16
__device__ __forceinline__ void gll16(const u16* g, u16* l) {
    __builtin_amdgcn_global_load_lds(
        (const __attribute__((address_space(1))) void*)(g),
        (__attribute__((address_space(3))) void*)(l), 16, 0, 0);
}

// ---------------------------------------------------------------------------
// split: fp32 [n] -> hi/lo bf16 [n].  8 elems per thread.
// ---------------------------------------------------------------------------
__global__ __launch_bounds__(256) void split_kernel(const float* __restrict__ in,
                                                    u16* __restrict__ hi,
                                                    u16* __restrict__ lo)
{
    const size_t i = ((size_t)blockIdx.x * 256 + threadIdx.x) * 8;
    float4 v0 = *(const float4*)(in + i);
    float4 v1 = *(const float4*)(in + i + 4);
    float xs[8] = {v0.x, v0.y, v0.z, v0.w, v1.x, v1.y, v1.z, v1.w};
    unsigned int hv[4], lv[4];
#pragma unroll
    for (int k = 0; k < 4; ++k) {
        u16 h0 = f2bf_rn(xs[2 * k]);
        u16 h1 = f2bf_rn(xs[2 * k + 1]);
        u16 l0 = f2bf_rn(xs[2 * k] - bf2f(h0));
        u16 l1 = f2bf_rn(xs[2 * k + 1] - bf2f(h1));
        hv[k] = (unsigned int)h0 | ((unsigned int)h1 << 16);
        lv[k] = (unsigned int)l0 | ((unsigned int)l1 << 16);
    }
    *(uint4*)(hi + i) = make_uint4(hv[0], hv[1], hv[2], hv[3]);
    *(uint4*)(lo + i) = make_uint4(lv[0], lv[1], lv[2], lv[3]);
}

// ---------------------------------------------------------------------------
// transpose+split: W [K][N] fp32 -> Th/Tl [N][K] bf16.  64x64 tiles via LDS.
// ---------------------------------------------------------------------------
__global__ __launch_bounds__(256) void tsplit_kernel(const float* __restrict__ W,
                                                     u16* __restrict__ Th,
                                                     u16* __restrict__ Tl,
                                                     int K, int N)
{
    __shared__ float t[64][65];
    const int kt = blockIdx.x, nt = blockIdx.y;
    const int c4 = (threadIdx.x & 15) * 4;
    const int r  = threadIdx.x >> 4;

#pragma unroll
    for (int s = 0; s < 4; ++s) {
        const int kk = r + s * 16;
        float4 v = *(const float4*)(W + (size_t)(kt * 64 + kk) * N + nt * 64 + c4);
        t[kk][c4 + 0] = v.x;
        t[kk][c4 + 1] = v.y;
        t[kk][c4 + 2] = v.z;
        t[kk][c4 + 3] = v.w;
    }
    __syncthreads();
#pragma unroll
    for (int s = 0; s < 4; ++s) {
        const int nn = r + s * 16;
        unsigned int hv[2], lv[2];
#pragma unroll
        for (int p = 0; p < 2; ++p) {
            u16 h0, h1, l0, l1;
            float x0 = t[c4 + 2 * p][nn];
            float x1 = t[c4 + 2 * p + 1][nn];
            h0 = f2bf_rn(x0); l0 = f2bf_rn(x0 - bf2f(h0));
            h1 = f2bf_rn(x1); l1 = f2bf_rn(x1 - bf2f(h1));
            hv[p] = (unsigned int)h0 | ((unsigned int)h1 << 16);
            lv[p] = (unsigned int)l0 | ((unsigned int)l1 << 16);
        }
        u16* ph = Th + (size_t)(nt * 64 + nn) * K + kt * 64 + c4;
        u16* pl = Tl + (size_t)(nt * 64 + nn) * K + kt * 64 + c4;
        *(uint2*)ph = make_uint2(hv[0], hv[1]);
        *(uint2*)pl = make_uint2(lv[0], lv[1]);
    }
}

// ---------------------------------------------------------------------------
// Split-bf16 MFMA GEMM tile: C = A @ B^T, 128x128, 4 waves, BK=32.
// Staging via global_load_lds width=16 (m97 technique): wave w stages rows
// [w*32, w*32+32) of each matrix; lane l -> row w*32+(l>>2), chunk (l&3)*8.
// LDS layout [row][32 u16] linear == base + lane*16 exactly.
// ---------------------------------------------------------------------------
__device__ __forceinline__ void mfma_gemm_tile(
    const u16* __restrict__ Ah, const u16* __restrict__ Al,
    const u16* __restrict__ Bh, const u16* __restrict__ Bl,
    float* __restrict__ C, const int Kd, const int ldc,
    const int bm0, const int bn0)
{
    __shared__ u16 ldsAh[128 * 32];
    __shared__ u16 ldsAl[128 * 32];
    __shared__ u16 ldsBh[128 * 32];
    __shared__ u16 ldsBl[128 * 32];

    const int tid  = threadIdx.x;
    const int lane = tid & 63;
    const int w    = tid >> 6;
    const int wr   = w >> 1, wc = w & 1;

    // per-lane staging source coords
    const int srow = w * 32 + (lane >> 2);
    const int schk = (lane & 3) * 8;
    const u16* gAh = Ah + (size_t)(bm0 + srow) * Kd + schk;
    const u16* gAl = Al + (size_t)(bm0 + srow) * Kd + schk;
    const u16* gBh = Bh + (size_t)(bn0 + srow) * Kd + schk;
    const u16* gBl = Bl + (size_t)(bn0 + srow) * Kd + schk;

    f32x4 acc[4][4];
#pragma unroll
    for (int i = 0; i < 4; ++i)
#pragma unroll
        for (int j = 0; j < 4; ++j) acc[i][j] = (f32x4){0.f, 0.f, 0.f, 0.f};

    const int fr = lane & 15;
    const int kb = (lane >> 4) * 8;

    for (int k0 = 0; k0 < Kd; k0 += 32) {
        if (k0) __syncthreads();
#pragma unroll
        for (int c = 0; c < 2; ++c) {
            const size_t go = (size_t)(c * 16) * Kd + k0;
            const int lb = (w * 32 + c * 16) * 32;
            gll16(gAh + go, &ldsAh[lb]);
            gll16(gAl + go, &ldsAl[lb]);
            gll16(gBh + go, &ldsBh[lb]);
            gll16(gBl + go, &ldsBl[lb]);
        }
        __syncthreads();   // compiler drains vmcnt(0) before s_barrier

        short8v a_h[4], a_l[4], b_h[4], b_l[4];
#pragma unroll
        for (int f = 0; f < 4; ++f) {
            const int ra = (wr * 64 + f * 16 + fr) * 32 + kb;
            const int rb = (wc * 64 + f * 16 + fr) * 32 + kb;
            a_h[f] = *(const short8v*)&ldsAh[ra];
            a_l[f] = *(const short8v*)&ldsAl[ra];
            b_h[f] = *(const short8v*)&ldsBh[rb];
            b_l[f] = *(const short8v*)&ldsBl[rb];
        }
#pragma unroll
        for (int i = 0; i < 4; ++i)
#pragma unroll
            for (int j = 0; j < 4; ++j) {
                acc[i][j] = __builtin_amdgcn_mfma_f32_16x16x32_bf16(a_h[i], b_h[j], acc[i][j], 0, 0, 0);
                acc[i][j] = __builtin_amdgcn_mfma_f32_16x16x32_bf16(a_h[i], b_l[j], acc[i][j], 0, 0, 0);
                acc[i][j] = __builtin_amdgcn_mfma_f32_16x16x32_bf16(a_l[i], b_h[j], acc[i][j], 0, 0, 0);
            }
    }

    const int cr = (lane >> 4) * 4;
    const int cc = lane & 15;
#pragma unroll
    for (int i = 0; i < 4; ++i)
#pragma unroll
        for (int j = 0; j < 4; ++j) {
#pragma unroll
            for (int r = 0; r < 4; ++r) {
                C[(size_t)(bm0 + wr * 64 + i * 16 + cr + r) * ldc
                  + (bn0 + wc * 64 + j * 16 + cc)] = acc[i][j][r];
            }
        }
}

__global__ __launch_bounds__(256, 2) void qkv_mfma_kernel(
    const u16* __restrict__ Xh, const u16* __restrict__ Xl,
    const u16* __restrict__ WqTh, const u16* __restrict__ WqTl,
    const u16* __restrict__ WkTh, const u16* __restrict__ WkTl,
    const u16* __restrict__ WvTh, const u16* __restrict__ WvTl,
    float* __restrict__ Qo, float* __restrict__ Ko, float* __restrict__ Vo)
{
    const int bn = blockIdx.x;
    const u16 *Bh, *Bl; float* C; int ldc, col0;
    if (bn < 16)      { Bh = WqTh; Bl = WqTl; C = Qo; ldc = NQ_;  col0 = bn * 128; }
    else if (bn < 18) { Bh = WkTh; Bl = WkTl; C = Ko; ldc = NKV_; col0 = (bn - 16) * 128; }
    else              { Bh = WvTh; Bl = WvTl; C = Vo; ldc = NKV_; col0 = (bn - 18) * 128; }
    mfma_gemm_tile(Xh, Xl, Bh, Bl, C, D_, ldc, blockIdx.y * 128, col0);
}

__global__ __launch_bounds__(256, 2) void out_mfma_kernel(
    const u16* __restrict__ Ch, const u16* __restrict__ Cl,
    const u16* __restrict__ WoTh, const u16* __restrict__ WoTl,
    float* __restrict__ Out)
{
    mfma_gemm_tile(Ch, Cl, WoTh, WoTl, Out, NQ_, D_, blockIdx.y * 128, blockIdx.x * 128);
}

// ---------------------------------------------------------------------------
// RoPE + split Q: Qw fp32 -> Qh/Ql bf16.
// ---------------------------------------------------------------------------
__global__ __launch_bounds__(128) void rope_split_q_kernel(
    const float* __restrict__ Qw, u16* __restrict__ Qh, u16* __restrict__ Ql)
{
    const int row = blockIdx.x;
    const int d = threadIdx.x;
    const int s = row & (S_ - 1);

    const float expo = (float)(2 * d) / (float)HD_;
    const float inv_freq = 1.0f / powf(10000.0f, expo);
    float sn, c;
    sincosf((float)s * inv_freq, &sn, &c);

    const float* qr = Qw + (size_t)row * NQ_;
    u16* qhr = Qh + (size_t)row * NQ_;
    u16* qlr = Ql + (size_t)row * NQ_;
#pragma unroll
    for (int h = 0; h < H_; ++h) {
        float x0 = qr[h * HD_ + d];
        float x1 = qr[h * HD_ + d + 128];
        float y0 = x0 * c - x1 * sn;
        float y1 = x1 * c + x0 * sn;
        u16 h0 = f2bf_rn(y0), h1 = f2bf_rn(y1);
        qhr[h * HD_ + d]       = h0;
        qhr[h * HD_ + d + 128] = h1;
        qlr[h * HD_ + d]       = f2bf_rn(y0 - bf2f(h0));
        qlr[h * HD_ + d + 128] = f2bf_rn(y1 - bf2f(h1));
    }
}

__global__ __launch_bounds__(128) void rope_split_k_kernel(
    const float* __restrict__ Kw, u16* __restrict__ Kh, u16* __restrict__ Kl)
{
    const int row = blockIdx.x;
    const int d = threadIdx.x;
    const int s = row & (S_ - 1);

    const float expo = (float)(2 * d) / (float)HD_;
    const float inv_freq = 1.0f / powf(10000.0f, expo);
    float sn, c;
    sincosf((float)s * inv_freq, &sn, &c);

    const float* kr = Kw + (size_t)row * HD_;
    float x0 = kr[d], x1 = kr[d + 128];
    float y0 = x0 * c - x1 * sn;
    float y1 = x1 * c + x0 * sn;
    u16 h0 = f2bf_rn(y0), h1 = f2bf_rn(y1);
    Kh[(size_t)row * HD_ + d]       = h0;
    Kh[(size_t)row * HD_ + d + 128] = h1;
    Kl[(size_t)row * HD_ + d]       = f2bf_rn(y0 - bf2f(h0));
    Kl[(size_t)row * HD_ + d + 128] = f2bf_rn(y1 - bf2f(h1));
}

// ---------------------------------------------------------------------------
// MFMA flash attention, split-bf16, causal, GQA(KV=1).
// QBLK=64 (4 waves x 16 q-rows), KVBLK=32, HD=256.
// T14 async-stage: next-K loads issued at top of QK phase, next-V loads at
// top of PV phase; LDS writes after the respective read-done barrier.
// P LDS stride 44 u16: scalar P-write banks kq*88%32+fr>>1 = disjoint.
// LPT: qt = 31-(u&31) so heaviest blocks dispatch first.
// ---------------------------------------------------------------------------
#define KVB_ 32
#define PBS_ 44

__global__ __launch_bounds__(256, 2) void attn_mfma_kernel(
    const u16* __restrict__ Qh, const u16* __restrict__ Ql,
    const u16* __restrict__ Kh, const u16* __restrict__ Kl,
    const u16* __restrict__ VtH, const u16* __restrict__ VtL,
    float* __restrict__ O)
{
    __shared__ u16 kv[2 * 256 * 40];     // K phase: 2 x 8192 u16; V phase: 2 x 10240
    __shared__ u16 pb[2 * 64 * PBS_];

    const int tid = threadIdx.x;
    const int lane = tid & 63;
    const int w = tid >> 6;

    const int u = blockIdx.x & 255;
    const int pair = blockIdx.x >> 8;
    const int qt = 31 - (u & 31);             // LPT: heavy first
    const int bh = (u >> 5) + pair * 8;
    const int b = bh >> 3, h = bh & 7;

    const int fr = lane & 15;
    const int kq = (lane >> 4);
    const int xm = fr & 7;

    // ---- Q fragments (hi/lo) to registers, loop-invariant ----
    short8v qfh[8], qfl[8];
    {
        const size_t qrow = (size_t)(b * S_ + qt * 64 + w * 16 + fr);
        const u16* ph = Qh + qrow * NQ_ + h * HD_ + kq * 8;
        const u16* pl = Ql + qrow * NQ_ + h * HD_ + kq * 8;
#pragma unroll
        for (int ks = 0; ks < 8; ++ks) {
            qfh[ks] = *(const short8v*)(ph + ks * 32);
            qfl[ks] = *(const short8v*)(pl + ks * 32);
        }
    }

    f32x4 oacc[16];
#pragma unroll
    for (int f = 0; f < 16; ++f) oacc[f] = (f32x4){0.f, 0.f, 0.f, 0.f};
    float m_i[4] = {-1e30f, -1e30f, -1e30f, -1e30f};
    float l_i[4] = {0.f, 0.f, 0.f, 0.f};

    const u16* ksrc[2] = {Kh + (size_t)b * S_ * HD_, Kl + (size_t)b * S_ * HD_};
    const u16* vsrc[2] = {VtH + (size_t)b * HD_ * S_, VtL + (size_t)b * HD_ * S_};

    const int nkt = (qt + 1) * 2;

    uint4 kreg[2][4], vreg[2][4];

    // ---- prologue: stage K(0) direct; prefetch V(0) into regs ----
#pragma unroll
    for (int c = 0; c < 2; ++c) {
        const u16* s = ksrc[c];
#pragma unroll
        for (int i = 0; i < 4; ++i) {
            const int chunk = i * 256 + tid;
            const int row = chunk >> 5, ch = chunk & 31;
            uint4 v = *(const uint4*)(s + (size_t)row * HD_ + ch * 8);
            *(uint4*)&kv[c * 8192 + row * 256 + (ch ^ (row & 7)) * 8] = v;
        }
    }
#pragma unroll
    for (int c = 0; c < 2; ++c) {
#pragma unroll
        for (int i = 0; i < 4; ++i) {
            const int chunk = i * 256 + tid;
            const int d = chunk >> 2, ch = chunk & 3;
            vreg[c][i] = *(const uint4*)(vsrc[c] + (size_t)d * S_ + ch * 8);
        }
    }
    __syncthreads();

    for (int kt = 0; kt < nkt; ++kt) {
        const bool more = (kt + 1 < nkt);

        // ---- prefetch next K into regs (hidden under QK + softmax) ----
        if (more) {
#pragma unroll
            for (int c = 0; c < 2; ++c) {
                const u16* s = ksrc[c] + (size_t)(kt + 1) * KVB_ * HD_;
#pragma unroll
                for (int i = 0; i < 4; ++i) {
                    const int chunk = i * 256 + tid;
                    const int row = chunk >> 5, ch = chunk & 31;
                    kreg[c][i] = *(const uint4*)(s + (size_t)row * HD_ + ch * 8);
                }
            }
        }

        // ---- QK^T: 2 n-frags, 8 k-steps, 3-term split ----
        f32x4 s0 = (f32x4){0.f, 0.f, 0.f, 0.f};
        f32x4 s1 = (f32x4){0.f, 0.f, 0.f, 0.f};
#pragma unroll
        for (int ks = 0; ks < 8; ++ks) {
            const int ch = (ks * 4 + kq) ^ xm;
            short8v kh0 = *(const short8v*)&kv[fr * 256 + ch * 8];
            short8v kh1 = *(const short8v*)&kv[(16 + fr) * 256 + ch * 8];
            short8v kl0 = *(const short8v*)&kv[8192 + fr * 256 + ch * 8];
            short8v kl1 = *(const short8v*)&kv[8192 + (16 + fr) * 256 + ch * 8];
            s0 = __builtin_amdgcn_mfma_f32_16x16x32_bf16(qfh[ks], kh0, s0, 0, 0, 0);
            s1 = __builtin_amdgcn_mfma_f32_16x16x32_bf16(qfh[ks], kh1, s1, 0, 0, 0);
            s0 = __builtin_amdgcn_mfma_f32_16x16x32_bf16(qfh[ks], kl0, s0, 0, 0, 0);
            s1 = __builtin_amdgcn_mfma_f32_16x16x32_bf16(qfh[ks], kl1, s1, 0, 0, 0);
            s0 = __builtin_amdgcn_mfma_f32_16x16x32_bf16(qfl[ks], kh0, s0, 0, 0, 0);
            s1 = __builtin_amdgcn_mfma_f32_16x16x32_bf16(qfl[ks], kh1, s1, 0, 0, 0);
        }

        // ---- online softmax + P write (stride 44) ----
        const int qglob = qt * 64 + w * 16 + kq * 4;
        const int kg = kt * KVB_ + fr;
#pragma unroll
        for (int r = 0; r < 4; ++r) {
            float x0 = s0[r] * 0.0625f;
            float x1 = s1[r] * 0.0625f;
            if (kg > qglob + r)      x0 = -1e30f;
            if (kg + 16 > qglob + r) x1 = -1e30f;
            float mx = fmaxf(x0, x1);
#pragma unroll
            for (int off = 1; off < 16; off <<= 1)
                mx = fmaxf(mx, __shfl_xor(mx, off, 64));
            const float mnew = fmaxf(m_i[r], mx);
            const float alpha = __expf(m_i[r] - mnew);
            const float p0 = __expf(x0 - mnew);
            const float p1 = __expf(x1 - mnew);
            float ps = p0 + p1;
#pragma unroll
            for (int off = 1; off < 16; off <<= 1)
                ps += __shfl_xor(ps, off, 64);
            l_i[r] = l_i[r] * alpha + ps;
            m_i[r] = mnew;
#pragma unroll
            for (int f = 0; f < 16; ++f) oacc[f][r] *= alpha;

            const int prow = (w * 16 + kq * 4 + r) * PBS_;
            u16 h0 = f2bf_rn(p0), h1 = f2bf_rn(p1);
            pb[prow + fr]                    = h0;
            pb[prow + 16 + fr]               = h1;
            pb[64 * PBS_ + prow + fr]        = f2bf_rn(p0 - bf2f(h0));
            pb[64 * PBS_ + prow + 16 + fr]   = f2bf_rn(p1 - bf2f(h1));
        }
        __syncthreads();   // bar1: all waves done reading K tile

        // ---- write V(kt) from regs ----
#pragma unroll
        for (int c = 0; c < 2; ++c)
#pragma unroll
            for (int i = 0; i < 4; ++i) {
                const int chunk = i * 256 + tid;
                const int d = chunk >> 2, ch = chunk & 3;
                *(uint4*)&kv[c * 10240 + d * 40 + ch * 8] = vreg[c][i];
            }
        __syncthreads();   // bar2: V visible

        // ---- prefetch next V into regs (hidden under PV) ----
        if (more) {
#pragma unroll
            for (int c = 0; c < 2; ++c) {
                const u16* s = vsrc[c] + (size_t)(kt + 1) * KVB_;
#pragma unroll
                for (int i = 0; i < 4; ++i) {
                    const int chunk = i * 256 + tid;
                    const int d = chunk >> 2, ch = chunk & 3;
                    vreg[c][i] = *(const uint4*)(s + (size_t)d * S_ + ch * 8);
                }
            }
        }

        // ---- PV ----
        {
            short8v pah = *(const short8v*)&pb[(w * 16 + fr) * PBS_ + kq * 8];
            short8v pal = *(const short8v*)&pb[64 * PBS_ + (w * 16 + fr) * PBS_ + kq * 8];
#pragma unroll
            for (int f = 0; f < 16; ++f) {
                const int vrow = (f * 16 + fr) * 40 + kq * 8;
                short8v vh = *(const short8v*)&kv[vrow];
                short8v vl = *(const short8v*)&kv[10240 + vrow];
                oacc[f] = __builtin_amdgcn_mfma_f32_16x16x32_bf16(pah, vh, oacc[f], 0, 0, 0);
                oacc[f] = __builtin_amdgcn_mfma_f32_16x16x32_bf16(pal, vh, oacc[f], 0, 0, 0);
                oacc[f] = __builtin_amdgcn_mfma_f32_16x16x32_bf16(pah, vl, oacc[f], 0, 0, 0);
            }
        }

        // ---- write K(kt+1) from regs ----
        if (more) {
            __syncthreads();   // bar3: all waves done reading V tile
#pragma unroll
            for (int c = 0; c < 2; ++c)
#pragma unroll
                for (int i = 0; i < 4; ++i) {
                    const int chunk = i * 256 + tid;
                    const int row = chunk >> 5, ch = chunk & 31;
                    *(uint4*)&kv[c * 8192 + row * 256 + (ch ^ (row & 7)) * 8] = kreg[c][i];
                }
            __syncthreads();   // bar4: K visible
        }
    }

    // ---- epilogue: O = oacc / l ----
    float* orow = O + (size_t)(b * S_ + qt * 64 + w * 16 + kq * 4) * NQ_ + h * HD_ + fr;
#pragma unroll
    for (int r = 0; r < 4; ++r) {
        const float inv_l = 1.0f / l_i[r];
#pragma unroll
        for (int f = 0; f < 16; ++f)
            orow[(size_t)r * NQ_ + f * 16] = oacc[f][r] * inv_l;
    }
}

// ---------------------------------------------------------------------------
extern "C" void kernel_launch(void* const* d_in, const int* in_sizes, int n_in,
                              void* d_out, int out_size, void* d_ws, size_t ws_size,
                              hipStream_t stream)
{
    (void)in_sizes; (void)n_in; (void)out_size; (void)ws_size;

    const float* hidden = (const float*)d_in[0];
    const float* Wq = (const float*)d_in[3];
    const float* Wk = (const float*)d_in[4];
    const float* Wv = (const float*)d_in[5];
    const float* Wo = (const float*)d_in[6];
    float* out = (float*)d_out;

    char* ws = (char*)d_ws;
    float* Qw = (float*)(ws + 0);
    u16* Kh2 = (u16*)(ws + 0);               // Qw region reused after rope_split_q
    u16* Kl2 = (u16*)(ws + 2097152u);
    u16* VtH = (u16*)(ws + 4194304u);
    u16* VtL = (u16*)(ws + 6291456u);
    float* Kw = (float*)(ws + 33554432u);
    float* Vw = (float*)(ws + 37748736u);
    float* Cw = (float*)(ws + 41943040u);
    u16* Ah  = (u16*)(ws + 75497472u);
    u16* Al  = (u16*)(ws + 92274688u);
    u16* WqTh = (u16*)(ws + 109051904u);
    u16* WqTl = (u16*)(ws + 117440512u);
    u16* WkTh = (u16*)(ws + 125829120u);
    u16* WkTl = (u16*)(ws + 126877696u);
    u16* WvTh = (u16*)(ws + 127926272u);
    u16* WvTl = (u16*)(ws + 128974848u);
    u16* WoTh = WqTh;
    u16* WoTl = WqTl;
    u16* Qhb = Ah;
    u16* Qlb = Al;

    split_kernel<<<dim3((M_ * D_) / (256 * 8)), dim3(256), 0, stream>>>(hidden, Ah, Al);

    tsplit_kernel<<<dim3(D_ / 64, NQ_ / 64),  dim3(256), 0, stream>>>(Wq, WqTh, WqTl, D_, NQ_);
    tsplit_kernel<<<dim3(D_ / 64, NKV_ / 64), dim3(256), 0, stream>>>(Wk, WkTh, WkTl, D_, NKV_);
    tsplit_kernel<<<dim3(D_ / 64, NKV_ / 64), dim3(256), 0, stream>>>(Wv, WvTh, WvTl, D_, NKV_);

    qkv_mfma_kernel<<<dim3(20, M_ / 128), dim3(256), 0, stream>>>(
        Ah, Al, WqTh, WqTl, WkTh, WkTl, WvTh, WvTl, Qw, Kw, Vw);

    rope_split_q_kernel<<<dim3(M_), dim3(128), 0, stream>>>(Qw, Qhb, Qlb);
    rope_split_k_kernel<<<dim3(M_), dim3(128), 0, stream>>>(Kw, Kh2, Kl2);

    tsplit_kernel<<<dim3(S_ / 64, NKV_ / 64), dim3(256), 0, stream>>>(
        Vw, VtH, VtL, S_, NKV_);
    tsplit_kernel<<<dim3(S_ / 64, NKV_ / 64), dim3(256), 0, stream>>>(
        Vw + (size_t)S_ * NKV_, VtH + (size_t)HD_ * S_, VtL + (size_t)HD_ * S_, S_, NKV_);

    attn_mfma_kernel<<<dim3(512), dim3(256), 0, stream>>>(
        Qhb, Qlb, Kh2, Kl2, VtH, VtL, Cw);

    split_kernel<<<dim3((M_ * NQ_) / (256 * 8)), dim3(256), 0, stream>>>(Cw, Ah, Al);

    tsplit_kernel<<<dim3(NQ_ / 64, D_ / 64), dim3(256), 0, stream>>>(Wo, WoTh, WoTl, NQ_, D_);

    out_mfma_kernel<<<dim3(D_ / 128, M_ / 128), dim3(256), 0, stream>>>(
        Ah, Al, WoTh, WoTl, out);
}

// Round 6
// 603.018 us; speedup vs baseline: 1.6883x; 1.6883x over previous
//
#include <hip/hip_runtime.h>
#include <cstdint>
#include <cstddef>

// Problem constants
#define B_   2
#define S_   2048
#define D_   2048
#define H_   8
#define HD_  256
#define M_   (B_ * S_)        // 4096 rows
#define NQ_  (H_ * HD_)       // 2048
#define NKV_ 256

typedef unsigned short u16;
typedef __attribute__((ext_vector_type(8))) short short8v;   // 8 bf16 (4 VGPRs)
typedef __attribute__((ext_vector_type(4))) float f32x4;     // MFMA acc frag

__device__ __forceinline__ u16 f2bf_rn(float x) {
    unsigned int u = __float_as_uint(x);
    unsigned int r = u + 0x7FFFu + ((u >> 16) & 1u);
    return (u16)(r >> 16);
}
__device__ __forceinline__ float bf2f(u16 h) {
    return __uint_as_float(((unsigned int)h) << 16);
}

// async global->LDS, 16B per lane; LDS dest = wave-uniform base + lane*16
__device__ __forceinline__ void gll16(const u16* g, u16* l) {
    __builtin_amdgcn_global_load_lds(
        (const __attribute__((address_space(1))) void*)(g),
        (__attribute__((address_space(3))) void*)(l), 16, 0, 0);
}

// ---------------------------------------------------------------------------
// split: fp32 [n] -> hi/lo bf16 [n].  8 elems per thread.
// ---------------------------------------------------------------------------
__global__ __launch_bounds__(256) void split_kernel(const float* __restrict__ in,
                                                    u16* __restrict__ hi,
                                                    u16* __restrict__ lo)
{
    const size_t i = ((size_t)blockIdx.x * 256 + threadIdx.x) * 8;
    float4 v0 = *(const float4*)(in + i);
    float4 v1 = *(const float4*)(in + i + 4);
    float xs[8] = {v0.x, v0.y, v0.z, v0.w, v1.x, v1.y, v1.z, v1.w};
    unsigned int hv[4], lv[4];
#pragma unroll
    for (int k = 0; k < 4; ++k) {
        u16 h0 = f2bf_rn(xs[2 * k]);
        u16 h1 = f2bf_rn(xs[2 * k + 1]);
        u16 l0 = f2bf_rn(xs[2 * k] - bf2f(h0));
        u16 l1 = f2bf_rn(xs[2 * k + 1] - bf2f(h1));
        hv[k] = (unsigned int)h0 | ((unsigned int)h1 << 16);
        lv[k] = (unsigned int)l0 | ((unsigned int)l1 << 16);
    }
    *(uint4*)(hi + i) = make_uint4(hv[0], hv[1], hv[2], hv[3]);
    *(uint4*)(lo + i) = make_uint4(lv[0], lv[1], lv[2], lv[3]);
}

// ---------------------------------------------------------------------------
// transpose+split: W [K][N] fp32 -> Th/Tl [N][K] bf16.  64x64 tiles via LDS.
// ---------------------------------------------------------------------------
__global__ __launch_bounds__(256) void tsplit_kernel(const float* __restrict__ W,
                                                     u16* __restrict__ Th,
                                                     u16* __restrict__ Tl,
                                                     int K, int N)
{
    __shared__ float t[64][65];
    const int kt = blockIdx.x, nt = blockIdx.y;
    const int c4 = (threadIdx.x & 15) * 4;
    const int r  = threadIdx.x >> 4;

#pragma unroll
    for (int s = 0; s < 4; ++s) {
        const int kk = r + s * 16;
        float4 v = *(const float4*)(W + (size_t)(kt * 64 + kk) * N + nt * 64 + c4);
        t[kk][c4 + 0] = v.x;
        t[kk][c4 + 1] = v.y;
        t[kk][c4 + 2] = v.z;
        t[kk][c4 + 3] = v.w;
    }
    __syncthreads();
#pragma unroll
    for (int s = 0; s < 4; ++s) {
        const int nn = r + s * 16;
        unsigned int hv[2], lv[2];
#pragma unroll
        for (int p = 0; p < 2; ++p) {
            u16 h0, h1, l0, l1;
            float x0 = t[c4 + 2 * p][nn];
            float x1 = t[c4 + 2 * p + 1][nn];
            h0 = f2bf_rn(x0); l0 = f2bf_rn(x0 - bf2f(h0));
            h1 = f2bf_rn(x1); l1 = f2bf_rn(x1 - bf2f(h1));
            hv[p] = (unsigned int)h0 | ((unsigned int)h1 << 16);
            lv[p] = (unsigned int)l0 | ((unsigned int)l1 << 16);
        }
        u16* ph = Th + (size_t)(nt * 64 + nn) * K + kt * 64 + c4;
        u16* pl = Tl + (size_t)(nt * 64 + nn) * K + kt * 64 + c4;
        *(uint2*)ph = make_uint2(hv[0], hv[1]);
        *(uint2*)pl = make_uint2(lv[0], lv[1]);
    }
}

// ---------------------------------------------------------------------------
// Split-bf16 MFMA GEMM tile (verified R5): C = A @ B^T, 128x128, 4 waves,
// BK=32, staging via global_load_lds width=16.
// ---------------------------------------------------------------------------
__device__ __forceinline__ void mfma_gemm_tile(
    const u16* __restrict__ Ah, const u16* __restrict__ Al,
    const u16* __restrict__ Bh, const u16* __restrict__ Bl,
    float* __restrict__ C, const int Kd, const int ldc,
    const int bm0, const int bn0)
{
    __shared__ u16 ldsAh[128 * 32];
    __shared__ u16 ldsAl[128 * 32];
    __shared__ u16 ldsBh[128 * 32];
    __shared__ u16 ldsBl[128 * 32];

    const int tid  = threadIdx.x;
    const int lane = tid & 63;
    const int w    = tid >> 6;
    const int wr   = w >> 1, wc = w & 1;

    const int srow = w * 32 + (lane >> 2);
    const int schk = (lane & 3) * 8;
    const u16* gAh = Ah + (size_t)(bm0 + srow) * Kd + schk;
    const u16* gAl = Al + (size_t)(bm0 + srow) * Kd + schk;
    const u16* gBh = Bh + (size_t)(bn0 + srow) * Kd + schk;
    const u16* gBl = Bl + (size_t)(bn0 + srow) * Kd + schk;

    f32x4 acc[4][4];
#pragma unroll
    for (int i = 0; i < 4; ++i)
#pragma unroll
        for (int j = 0; j < 4; ++j) acc[i][j] = (f32x4){0.f, 0.f, 0.f, 0.f};

    const int fr = lane & 15;
    const int kb = (lane >> 4) * 8;

    for (int k0 = 0; k0 < Kd; k0 += 32) {
        if (k0) __syncthreads();
#pragma unroll
        for (int c = 0; c < 2; ++c) {
            const size_t go = (size_t)(c * 16) * Kd + k0;
            const int lb = (w * 32 + c * 16) * 32;
            gll16(gAh + go, &ldsAh[lb]);
            gll16(gAl + go, &ldsAl[lb]);
            gll16(gBh + go, &ldsBh[lb]);
            gll16(gBl + go, &ldsBl[lb]);
        }
        __syncthreads();

        short8v a_h[4], a_l[4], b_h[4], b_l[4];
#pragma unroll
        for (int f = 0; f < 4; ++f) {
            const int ra = (wr * 64 + f * 16 + fr) * 32 + kb;
            const int rb = (wc * 64 + f * 16 + fr) * 32 + kb;
            a_h[f] = *(const short8v*)&ldsAh[ra];
            a_l[f] = *(const short8v*)&ldsAl[ra];
            b_h[f] = *(const short8v*)&ldsBh[rb];
            b_l[f] = *(const short8v*)&ldsBl[rb];
        }
#pragma unroll
        for (int i = 0; i < 4; ++i)
#pragma unroll
            for (int j = 0; j < 4; ++j) {
                acc[i][j] = __builtin_amdgcn_mfma_f32_16x16x32_bf16(a_h[i], b_h[j], acc[i][j], 0, 0, 0);
                acc[i][j] = __builtin_amdgcn_mfma_f32_16x16x32_bf16(a_h[i], b_l[j], acc[i][j], 0, 0, 0);
                acc[i][j] = __builtin_amdgcn_mfma_f32_16x16x32_bf16(a_l[i], b_h[j], acc[i][j], 0, 0, 0);
            }
    }

    const int cr = (lane >> 4) * 4;
    const int cc = lane & 15;
#pragma unroll
    for (int i = 0; i < 4; ++i)
#pragma unroll
        for (int j = 0; j < 4; ++j) {
#pragma unroll
            for (int r = 0; r < 4; ++r) {
                C[(size_t)(bm0 + wr * 64 + i * 16 + cr + r) * ldc
                  + (bn0 + wc * 64 + j * 16 + cc)] = acc[i][j][r];
            }
        }
}

__global__ __launch_bounds__(256, 2) void qkv_mfma_kernel(
    const u16* __restrict__ Xh, const u16* __restrict__ Xl,
    const u16* __restrict__ WqTh, const u16* __restrict__ WqTl,
    const u16* __restrict__ WkTh, const u16* __restrict__ WkTl,
    const u16* __restrict__ WvTh, const u16* __restrict__ WvTl,
    float* __restrict__ Qo, float* __restrict__ Ko, float* __restrict__ Vo)
{
    const int bn = blockIdx.x;
    const u16 *Bh, *Bl; float* C; int ldc, col0;
    if (bn < 16)      { Bh = WqTh; Bl = WqTl; C = Qo; ldc = NQ_;  col0 = bn * 128; }
    else if (bn < 18) { Bh = WkTh; Bl = WkTl; C = Ko; ldc = NKV_; col0 = (bn - 16) * 128; }
    else              { Bh = WvTh; Bl = WvTl; C = Vo; ldc = NKV_; col0 = (bn - 18) * 128; }
    mfma_gemm_tile(Xh, Xl, Bh, Bl, C, D_, ldc, blockIdx.y * 128, col0);
}

__global__ __launch_bounds__(256, 2) void out_mfma_kernel(
    const u16* __restrict__ Ch, const u16* __restrict__ Cl,
    const u16* __restrict__ WoTh, const u16* __restrict__ WoTl,
    float* __restrict__ Out)
{
    mfma_gemm_tile(Ch, Cl, WoTh, WoTl, Out, NQ_, D_, blockIdx.y * 128, blockIdx.x * 128);
}

// ---------------------------------------------------------------------------
// RoPE + split Q: Qw fp32 -> Qh/Ql bf16.
// ---------------------------------------------------------------------------
__global__ __launch_bounds__(128) void rope_split_q_kernel(
    const float* __restrict__ Qw, u16* __restrict__ Qh, u16* __restrict__ Ql)
{
    const int row = blockIdx.x;
    const int d = threadIdx.x;
    const int s = row & (S_ - 1);

    const float expo = (float)(2 * d) / (float)HD_;
    const float inv_freq = 1.0f / powf(10000.0f, expo);
    float sn, c;
    sincosf((float)s * inv_freq, &sn, &c);

    const float* qr = Qw + (size_t)row * NQ_;
    u16* qhr = Qh + (size_t)row * NQ_;
    u16* qlr = Ql + (size_t)row * NQ_;
#pragma unroll
    for (int h = 0; h < H_; ++h) {
        float x0 = qr[h * HD_ + d];
        float x1 = qr[h * HD_ + d + 128];
        float y0 = x0 * c - x1 * sn;
        float y1 = x1 * c + x0 * sn;
        u16 h0 = f2bf_rn(y0), h1 = f2bf_rn(y1);
        qhr[h * HD_ + d]       = h0;
        qhr[h * HD_ + d + 128] = h1;
        qlr[h * HD_ + d]       = f2bf_rn(y0 - bf2f(h0));
        qlr[h * HD_ + d + 128] = f2bf_rn(y1 - bf2f(h1));
    }
}

// RoPE + split K, written PRE-SWIZZLED for linear global_load_lds staging:
// G[row][ ((dd>>3)^(row&7))*8 + (dd&7) ] = K_rope[row][dd]
__global__ __launch_bounds__(128) void rope_split_k_swz_kernel(
    const float* __restrict__ Kw, u16* __restrict__ Kh, u16* __restrict__ Kl)
{
    const int row = blockIdx.x;
    const int d = threadIdx.x;
    const int s = row & (S_ - 1);
    const int xm = row & 7;

    const float expo = (float)(2 * d) / (float)HD_;
    const float inv_freq = 1.0f / powf(10000.0f, expo);
    float sn, c;
    sincosf((float)s * inv_freq, &sn, &c);

    const float* kr = Kw + (size_t)row * HD_;
    float x0 = kr[d], x1 = kr[d + 128];
    float y0 = x0 * c - x1 * sn;
    float y1 = x1 * c + x0 * sn;
    u16 h0 = f2bf_rn(y0), h1 = f2bf_rn(y1);

    const int o0 = (((d >> 3) ^ xm) << 3) | (d & 7);
    const int o1 = ((((d + 128) >> 3) ^ xm) << 3) | (d & 7);
    Kh[(size_t)row * HD_ + o0] = h0;
    Kh[(size_t)row * HD_ + o1] = h1;
    Kl[(size_t)row * HD_ + o0] = f2bf_rn(y0 - bf2f(h0));
    Kl[(size_t)row * HD_ + o1] = f2bf_rn(y1 - bf2f(h1));
}

// ---------------------------------------------------------------------------
// MFMA flash attention, split-bf16, causal, GQA(KV=1).
// QBLK=64 (4 waves x 16 q-rows), KVBLK=32, HD=256.
// 2-phase async pipeline with global_load_lds:
//   QK(K) -> softmax/P -> barA(frees K, drains V(kt)) -> issue K(kt+1)
//   -> PV(V) -> barB(frees V, drains K(kt+1)) -> issue V(kt+1)
// K source pre-swizzled (rule #21), V LDS linear [256][32].
// T13 defer-max (THR=8, wave-level).
// ---------------------------------------------------------------------------
#define KVB_ 32
#define PBS_ 44

__global__ __launch_bounds__(256, 2) void attn_mfma_kernel(
    const u16* __restrict__ Qh, const u16* __restrict__ Ql,
    const u16* __restrict__ Kh, const u16* __restrict__ Kl,
    const u16* __restrict__ VtH, const u16* __restrict__ VtL,
    float* __restrict__ O)
{
    __shared__ u16 kvK[2 * 32 * 256];   // [c][row 0..31][256], swizzled payload
    __shared__ u16 kvV[2 * 256 * 32];   // [c][d 0..255][32]
    __shared__ u16 pb[2 * 64 * PBS_];

    const int tid = threadIdx.x;
    const int lane = tid & 63;
    const int w = tid >> 6;

    // balanced pairing: block i and i+256 get complementary qt
    const int u = blockIdx.x & 255;
    const int pair = blockIdx.x >> 8;
    const int qt_base = u & 31;
    const int qt = pair ? (31 - qt_base) : qt_base;
    const int bh = (u >> 5) + pair * 8;
    const int b = bh >> 3, h = bh & 7;

    const int fr = lane & 15;
    const int kq = (lane >> 4);
    const int xm = fr & 7;

    // ---- Q fragments (hi/lo) to registers, loop-invariant ----
    short8v qfh[8], qfl[8];
    {
        const size_t qrow = (size_t)(b * S_ + qt * 64 + w * 16 + fr);
        const u16* ph = Qh + qrow * NQ_ + h * HD_ + kq * 8;
        const u16* pl = Ql + qrow * NQ_ + h * HD_ + kq * 8;
#pragma unroll
        for (int ks = 0; ks < 8; ++ks) {
            qfh[ks] = *(const short8v*)(ph + ks * 32);
            qfl[ks] = *(const short8v*)(pl + ks * 32);
        }
    }

    f32x4 oacc[16];
#pragma unroll
    for (int f = 0; f < 16; ++f) oacc[f] = (f32x4){0.f, 0.f, 0.f, 0.f};
    float m_i[4] = {-1e30f, -1e30f, -1e30f, -1e30f};
    float l_i[4] = {0.f, 0.f, 0.f, 0.f};

    const u16* ksrc[2] = {Kh + (size_t)b * S_ * HD_, Kl + (size_t)b * S_ * HD_};
    const u16* vsrc[2] = {VtH + (size_t)b * HD_ * S_, VtL + (size_t)b * HD_ * S_};

    // per-lane staging source coords (K): row_local = w*8+t*2+(lane>>5), ch=lane&31
    const int k_rl = w * 8 + (lane >> 5) * 0;   // base; t*2+(lane>>5) added per t
    const int k_hi = (lane >> 5);               // 0/1
    const int k_ch = lane & 31;
    // per-lane staging source coords (V): d = w*64+t*16+(lane>>2), col=(lane&3)*8
    const int v_dl = w * 64 + (lane >> 2);
    const int v_cc = (lane & 3) * 8;

    const int nkt = (qt + 1) * 2;

#define STAGE_K(KT)                                                            \
    {                                                                          \
        _Pragma("unroll")                                                      \
        for (int c = 0; c < 2; ++c) {                                          \
            _Pragma("unroll")                                                  \
            for (int t = 0; t < 4; ++t) {                                      \
                const int rl = k_rl + t * 2 + k_hi;                            \
                gll16(ksrc[c] + (size_t)((KT) * KVB_ + rl) * HD_ + k_ch * 8,   \
                      &kvK[c * 8192 + (w * 2048 + t * 512)]);                  \
            }                                                                  \
        }                                                                      \
    }

#define STAGE_V(KT)                                                            \
    {                                                                          \
        _Pragma("unroll")                                                      \
        for (int c = 0; c < 2; ++c) {                                          \
            _Pragma("unroll")                                                  \
            for (int t = 0; t < 4; ++t) {                                      \
                gll16(vsrc[c] + (size_t)(v_dl + t * 16) * S_ + (KT) * KVB_ + v_cc, \
                      &kvV[c * 8192 + (w * 2048 + t * 512)]);                  \
            }                                                                  \
        }                                                                      \
    }

    // ---- prologue: stage K(0), V(0); barrier drains both ----
    STAGE_K(0)
    STAGE_V(0)
    __syncthreads();

    for (int kt = 0; kt < nkt; ++kt) {
        const bool more = (kt + 1 < nkt);

        // ---- QK^T: 2 n-frags, 8 k-steps, 3-term split ----
        f32x4 s0 = (f32x4){0.f, 0.f, 0.f, 0.f};
        f32x4 s1 = (f32x4){0.f, 0.f, 0.f, 0.f};
#pragma unroll
        for (int ks = 0; ks < 8; ++ks) {
            const int ch = (ks * 4 + kq) ^ xm;
            short8v kh0 = *(const short8v*)&kvK[fr * 256 + ch * 8];
            short8v kh1 = *(const short8v*)&kvK[(16 + fr) * 256 + ch * 8];
            short8v kl0 = *(const short8v*)&kvK[8192 + fr * 256 + ch * 8];
            short8v kl1 = *(const short8v*)&kvK[8192 + (16 + fr) * 256 + ch * 8];
            s0 = __builtin_amdgcn_mfma_f32_16x16x32_bf16(qfh[ks], kh0, s0, 0, 0, 0);
            s1 = __builtin_amdgcn_mfma_f32_16x16x32_bf16(qfh[ks], kh1, s1, 0, 0, 0);
            s0 = __builtin_amdgcn_mfma_f32_16x16x32_bf16(qfh[ks], kl0, s0, 0, 0, 0);
            s1 = __builtin_amdgcn_mfma_f32_16x16x32_bf16(qfh[ks], kl1, s1, 0, 0, 0);
            s0 = __builtin_amdgcn_mfma_f32_16x16x32_bf16(qfl[ks], kh0, s0, 0, 0, 0);
            s1 = __builtin_amdgcn_mfma_f32_16x16x32_bf16(qfl[ks], kh1, s1, 0, 0, 0);
        }

        // ---- online softmax with T13 defer-max ----
        const int qglob = qt * 64 + w * 16 + kq * 4;
        const int kg = kt * KVB_ + fr;
        float mxv[4];
        bool need = false;
#pragma unroll
        for (int r = 0; r < 4; ++r) {
            float x0 = s0[r] * 0.0625f;
            float x1 = s1[r] * 0.0625f;
            if (kg > qglob + r)      x0 = -1e30f;
            if (kg + 16 > qglob + r) x1 = -1e30f;
            s0[r] = x0; s1[r] = x1;
            float mx = fmaxf(x0, x1);
#pragma unroll
            for (int off = 1; off < 16; off <<= 1)
                mx = fmaxf(mx, __shfl_xor(mx, off, 64));
            mxv[r] = mx;
            need = need || (mx > m_i[r] + 8.0f);
        }
        if (__any((int)need)) {
#pragma unroll
            for (int r = 0; r < 4; ++r) {
                const float mnew = fmaxf(m_i[r], mxv[r]);
                const float alpha = __expf(m_i[r] - mnew);
                l_i[r] *= alpha;
                m_i[r] = mnew;
#pragma unroll
                for (int f = 0; f < 16; ++f) oacc[f][r] *= alpha;
            }
        }
#pragma unroll
        for (int r = 0; r < 4; ++r) {
            const float p0 = __expf(s0[r] - m_i[r]);
            const float p1 = __expf(s1[r] - m_i[r]);
            float ps = p0 + p1;
#pragma unroll
            for (int off = 1; off < 16; off <<= 1)
                ps += __shfl_xor(ps, off, 64);
            l_i[r] += ps;

            const int prow = (w * 16 + kq * 4 + r) * PBS_;
            u16 h0 = f2bf_rn(p0), h1 = f2bf_rn(p1);
            pb[prow + fr]                    = h0;
            pb[prow + 16 + fr]               = h1;
            pb[64 * PBS_ + prow + fr]        = f2bf_rn(p0 - bf2f(h0));
            pb[64 * PBS_ + prow + 16 + fr]   = f2bf_rn(p1 - bf2f(h1));
        }
        __syncthreads();   // barA: K free, P visible, V(kt) loads drained

        // ---- issue K(kt+1) (hidden under PV) ----
        if (more) STAGE_K(kt + 1)

        // ---- PV: A = P (own stripe), B = V frags from [256][32] ----
        {
            short8v pah = *(const short8v*)&pb[(w * 16 + fr) * PBS_ + kq * 8];
            short8v pal = *(const short8v*)&pb[64 * PBS_ + (w * 16 + fr) * PBS_ + kq * 8];
#pragma unroll
            for (int f = 0; f < 16; ++f) {
                const int vrow = (f * 16 + fr) * 32 + kq * 8;
                short8v vh = *(const short8v*)&kvV[vrow];
                short8v vl = *(const short8v*)&kvV[8192 + vrow];
                oacc[f] = __builtin_amdgcn_mfma_f32_16x16x32_bf16(pah, vh, oacc[f], 0, 0, 0);
                oacc[f] = __builtin_amdgcn_mfma_f32_16x16x32_bf16(pal, vh, oacc[f], 0, 0, 0);
                oacc[f] = __builtin_amdgcn_mfma_f32_16x16x32_bf16(pah, vl, oacc[f], 0, 0, 0);
            }
        }
        if (more) {
            __syncthreads();   // barB: V free, K(kt+1) loads drained
            STAGE_V(kt + 1)
        }
    }

    // ---- epilogue: O = oacc / l ----
    float* orow = O + (size_t)(b * S_ + qt * 64 + w * 16 + kq * 4) * NQ_ + h * HD_ + fr;
#pragma unroll
    for (int r = 0; r < 4; ++r) {
        const float inv_l = 1.0f / l_i[r];
#pragma unroll
        for (int f = 0; f < 16; ++f)
            orow[(size_t)r * NQ_ + f * 16] = oacc[f][r] * inv_l;
    }
#undef STAGE_K
#undef STAGE_V
}

// ---------------------------------------------------------------------------
extern "C" void kernel_launch(void* const* d_in, const int* in_sizes, int n_in,
                              void* d_out, int out_size, void* d_ws, size_t ws_size,
                              hipStream_t stream)
{
    (void)in_sizes; (void)n_in; (void)out_size; (void)ws_size;

    const float* hidden = (const float*)d_in[0];
    const float* Wq = (const float*)d_in[3];
    const float* Wk = (const float*)d_in[4];
    const float* Wv = (const float*)d_in[5];
    const float* Wo = (const float*)d_in[6];
    float* out = (float*)d_out;

    char* ws = (char*)d_ws;
    float* Qw = (float*)(ws + 0);
    u16* Kh2 = (u16*)(ws + 0);               // Qw region reused after rope_split_q
    u16* Kl2 = (u16*)(ws + 2097152u);
    u16* VtH = (u16*)(ws + 4194304u);
    u16* VtL = (u16*)(ws + 6291456u);
    float* Kw = (float*)(ws + 33554432u);
    float* Vw = (float*)(ws + 37748736u);
    float* Cw = (float*)(ws + 41943040u);
    u16* Ah  = (u16*)(ws + 75497472u);
    u16* Al  = (u16*)(ws + 92274688u);
    u16* WqTh = (u16*)(ws + 109051904u);
    u16* WqTl = (u16*)(ws + 117440512u);
    u16* WkTh = (u16*)(ws + 125829120u);
    u16* WkTl = (u16*)(ws + 126877696u);
    u16* WvTh = (u16*)(ws + 127926272u);
    u16* WvTl = (u16*)(ws + 128974848u);
    u16* WoTh = WqTh;
    u16* WoTl = WqTl;
    u16* Qhb = Ah;
    u16* Qlb = Al;

    split_kernel<<<dim3((M_ * D_) / (256 * 8)), dim3(256), 0, stream>>>(hidden, Ah, Al);

    tsplit_kernel<<<dim3(D_ / 64, NQ_ / 64),  dim3(256), 0, stream>>>(Wq, WqTh, WqTl, D_, NQ_);
    tsplit_kernel<<<dim3(D_ / 64, NKV_ / 64), dim3(256), 0, stream>>>(Wk, WkTh, WkTl, D_, NKV_);
    tsplit_kernel<<<dim3(D_ / 64, NKV_ / 64), dim3(256), 0, stream>>>(Wv, WvTh, WvTl, D_, NKV_);

    qkv_mfma_kernel<<<dim3(20, M_ / 128), dim3(256), 0, stream>>>(
        Ah, Al, WqTh, WqTl, WkTh, WkTl, WvTh, WvTl, Qw, Kw, Vw);

    rope_split_q_kernel<<<dim3(M_), dim3(128), 0, stream>>>(Qw, Qhb, Qlb);
    rope_split_k_swz_kernel<<<dim3(M_), dim3(128), 0, stream>>>(Kw, Kh2, Kl2);

    tsplit_kernel<<<dim3(S_ / 64, NKV_ / 64), dim3(256), 0, stream>>>(
        Vw, VtH, VtL, S_, NKV_);
    tsplit_kernel<<<dim3(S_ / 64, NKV_ / 64), dim3(256), 0, stream>>>(
        Vw + (size_t)S_ * NKV_, VtH + (size_t)HD_ * S_, VtL + (size_t)HD_ * S_, S_, NKV_);

    attn_mfma_kernel<<<dim3(512), dim3(256), 0, stream>>>(
        Qhb, Qlb, Kh2, Kl2, VtH, VtL, Cw);

    split_kernel<<<dim3((M_ * NQ_) / (256 * 8)), dim3(256), 0, stream>>>(Cw, Ah, Al);

    tsplit_kernel<<<dim3(NQ_ / 64, D_ / 64), dim3(256), 0, stream>>>(Wo, WoTh, WoTl, NQ_, D_);

    out_mfma_kernel<<<dim3(D_ / 128, M_ / 128), dim3(256), 0, stream>>>(
        Ah, Al, WoTh, WoTl, out);
}

// Round 7
// 579.175 us; speedup vs baseline: 1.7578x; 1.0412x over previous
//
#include <hip/hip_runtime.h>
#include <cstdint>
#include <cstddef>

// Problem constants
#define B_   2
#define S_   2048
#define D_   2048
#define H_   8
#define HD_  256
#define M_   (B_ * S_)        // 4096 rows
#define NQ_  (H_ * HD_)       // 2048
#define NKV_ 256

typedef unsigned short u16;
typedef __attribute__((ext_vector_type(8))) short short8v;   // 8 bf16 (4 VGPRs)
typedef __attribute__((ext_vector_type(4))) float f32x4;     // MFMA acc frag

__device__ __forceinline__ u16 f2bf_rn(float x) {
    unsigned int u = __float_as_uint(x);
    unsigned int r = u + 0x7FFFu + ((u >> 16) & 1u);
    return (u16)(r >> 16);
}
__device__ __forceinline__ float bf2f(u16 h) {
    return __uint_as_float(((unsigned int)h) << 16);
}

// async global->LDS, 16B per lane; LDS dest = wave-uniform base + lane*16
__device__ __forceinline__ void gll16(const u16* g, u16* l) {
    __builtin_amdgcn_global_load_lds(
        (const __attribute__((address_space(1))) void*)(g),
        (__attribute__((address_space(3))) void*)(l), 16, 0, 0);
}

// ---------------------------------------------------------------------------
// split: fp32 [n] -> hi/lo bf16 [n].  8 elems per thread.
// ---------------------------------------------------------------------------
__global__ __launch_bounds__(256) void split_kernel(const float* __restrict__ in,
                                                    u16* __restrict__ hi,
                                                    u16* __restrict__ lo)
{
    const size_t i = ((size_t)blockIdx.x * 256 + threadIdx.x) * 8;
    float4 v0 = *(const float4*)(in + i);
    float4 v1 = *(const float4*)(in + i + 4);
    float xs[8] = {v0.x, v0.y, v0.z, v0.w, v1.x, v1.y, v1.z, v1.w};
    unsigned int hv[4], lv[4];
#pragma unroll
    for (int k = 0; k < 4; ++k) {
        u16 h0 = f2bf_rn(xs[2 * k]);
        u16 h1 = f2bf_rn(xs[2 * k + 1]);
        u16 l0 = f2bf_rn(xs[2 * k] - bf2f(h0));
        u16 l1 = f2bf_rn(xs[2 * k + 1] - bf2f(h1));
        hv[k] = (unsigned int)h0 | ((unsigned int)h1 << 16);
        lv[k] = (unsigned int)l0 | ((unsigned int)l1 << 16);
    }
    *(uint4*)(hi + i) = make_uint4(hv[0], hv[1], hv[2], hv[3]);
    *(uint4*)(lo + i) = make_uint4(lv[0], lv[1], lv[2], lv[3]);
}

// ---------------------------------------------------------------------------
// transpose+split: W [K][N] fp32 -> Th/Tl [N][K] bf16.  64x64 tiles via LDS.
// ---------------------------------------------------------------------------
__global__ __launch_bounds__(256) void tsplit_kernel(const float* __restrict__ W,
                                                     u16* __restrict__ Th,
                                                     u16* __restrict__ Tl,
                                                     int K, int N)
{
    __shared__ float t[64][65];
    const int kt = blockIdx.x, nt = blockIdx.y;
    const int c4 = (threadIdx.x & 15) * 4;
    const int r  = threadIdx.x >> 4;

#pragma unroll
    for (int s = 0; s < 4; ++s) {
        const int kk = r + s * 16;
        float4 v = *(const float4*)(W + (size_t)(kt * 64 + kk) * N + nt * 64 + c4);
        t[kk][c4 + 0] = v.x;
        t[kk][c4 + 1] = v.y;
        t[kk][c4 + 2] = v.z;
        t[kk][c4 + 3] = v.w;
    }
    __syncthreads();
#pragma unroll
    for (int s = 0; s < 4; ++s) {
        const int nn = r + s * 16;
        unsigned int hv[2], lv[2];
#pragma unroll
        for (int p = 0; p < 2; ++p) {
            u16 h0, h1, l0, l1;
            float x0 = t[c4 + 2 * p][nn];
            float x1 = t[c4 + 2 * p + 1][nn];
            h0 = f2bf_rn(x0); l0 = f2bf_rn(x0 - bf2f(h0));
            h1 = f2bf_rn(x1); l1 = f2bf_rn(x1 - bf2f(h1));
            hv[p] = (unsigned int)h0 | ((unsigned int)h1 << 16);
            lv[p] = (unsigned int)l0 | ((unsigned int)l1 << 16);
        }
        u16* ph = Th + (size_t)(nt * 64 + nn) * K + kt * 64 + c4;
        u16* pl = Tl + (size_t)(nt * 64 + nn) * K + kt * 64 + c4;
        *(uint2*)ph = make_uint2(hv[0], hv[1]);
        *(uint2*)pl = make_uint2(lv[0], lv[1]);
    }
}

// ---------------------------------------------------------------------------
// Split-bf16 MFMA GEMM tile (verified R5/R6): C = A @ B^T, 128x128, 4 waves,
// BK=32, staging via global_load_lds width=16.
// ---------------------------------------------------------------------------
__device__ __forceinline__ void mfma_gemm_tile(
    const u16* __restrict__ Ah, const u16* __restrict__ Al,
    const u16* __restrict__ Bh, const u16* __restrict__ Bl,
    float* __restrict__ C, const int Kd, const int ldc,
    const int bm0, const int bn0)
{
    __shared__ u16 ldsAh[128 * 32];
    __shared__ u16 ldsAl[128 * 32];
    __shared__ u16 ldsBh[128 * 32];
    __shared__ u16 ldsBl[128 * 32];

    const int tid  = threadIdx.x;
    const int lane = tid & 63;
    const int w    = tid >> 6;
    const int wr   = w >> 1, wc = w & 1;

    const int srow = w * 32 + (lane >> 2);
    const int schk = (lane & 3) * 8;
    const u16* gAh = Ah + (size_t)(bm0 + srow) * Kd + schk;
    const u16* gAl = Al + (size_t)(bm0 + srow) * Kd + schk;
    const u16* gBh = Bh + (size_t)(bn0 + srow) * Kd + schk;
    const u16* gBl = Bl + (size_t)(bn0 + srow) * Kd + schk;

    f32x4 acc[4][4];
#pragma unroll
    for (int i = 0; i < 4; ++i)
#pragma unroll
        for (int j = 0; j < 4; ++j) acc[i][j] = (f32x4){0.f, 0.f, 0.f, 0.f};

    const int fr = lane & 15;
    const int kb = (lane >> 4) * 8;

    for (int k0 = 0; k0 < Kd; k0 += 32) {
        if (k0) __syncthreads();
#pragma unroll
        for (int c = 0; c < 2; ++c) {
            const size_t go = (size_t)(c * 16) * Kd + k0;
            const int lb = (w * 32 + c * 16) * 32;
            gll16(gAh + go, &ldsAh[lb]);
            gll16(gAl + go, &ldsAl[lb]);
            gll16(gBh + go, &ldsBh[lb]);
            gll16(gBl + go, &ldsBl[lb]);
        }
        __syncthreads();

        short8v a_h[4], a_l[4], b_h[4], b_l[4];
#pragma unroll
        for (int f = 0; f < 4; ++f) {
            const int ra = (wr * 64 + f * 16 + fr) * 32 + kb;
            const int rb = (wc * 64 + f * 16 + fr) * 32 + kb;
            a_h[f] = *(const short8v*)&ldsAh[ra];
            a_l[f] = *(const short8v*)&ldsAl[ra];
            b_h[f] = *(const short8v*)&ldsBh[rb];
            b_l[f] = *(const short8v*)&ldsBl[rb];
        }
#pragma unroll
        for (int i = 0; i < 4; ++i)
#pragma unroll
            for (int j = 0; j < 4; ++j) {
                acc[i][j] = __builtin_amdgcn_mfma_f32_16x16x32_bf16(a_h[i], b_h[j], acc[i][j], 0, 0, 0);
                acc[i][j] = __builtin_amdgcn_mfma_f32_16x16x32_bf16(a_h[i], b_l[j], acc[i][j], 0, 0, 0);
                acc[i][j] = __builtin_amdgcn_mfma_f32_16x16x32_bf16(a_l[i], b_h[j], acc[i][j], 0, 0, 0);
            }
    }

    const int cr = (lane >> 4) * 4;
    const int cc = lane & 15;
#pragma unroll
    for (int i = 0; i < 4; ++i)
#pragma unroll
        for (int j = 0; j < 4; ++j) {
#pragma unroll
            for (int r = 0; r < 4; ++r) {
                C[(size_t)(bm0 + wr * 64 + i * 16 + cr + r) * ldc
                  + (bn0 + wc * 64 + j * 16 + cc)] = acc[i][j][r];
            }
        }
}

__global__ __launch_bounds__(256, 2) void qkv_mfma_kernel(
    const u16* __restrict__ Xh, const u16* __restrict__ Xl,
    const u16* __restrict__ WqTh, const u16* __restrict__ WqTl,
    const u16* __restrict__ WkTh, const u16* __restrict__ WkTl,
    const u16* __restrict__ WvTh, const u16* __restrict__ WvTl,
    float* __restrict__ Qo, float* __restrict__ Ko, float* __restrict__ Vo)
{
    const int bn = blockIdx.x;
    const u16 *Bh, *Bl; float* C; int ldc, col0;
    if (bn < 16)      { Bh = WqTh; Bl = WqTl; C = Qo; ldc = NQ_;  col0 = bn * 128; }
    else if (bn < 18) { Bh = WkTh; Bl = WkTl; C = Ko; ldc = NKV_; col0 = (bn - 16) * 128; }
    else              { Bh = WvTh; Bl = WvTl; C = Vo; ldc = NKV_; col0 = (bn - 18) * 128; }
    mfma_gemm_tile(Xh, Xl, Bh, Bl, C, D_, ldc, blockIdx.y * 128, col0);
}

__global__ __launch_bounds__(256, 2) void out_mfma_kernel(
    const u16* __restrict__ Ch, const u16* __restrict__ Cl,
    const u16* __restrict__ WoTh, const u16* __restrict__ WoTl,
    float* __restrict__ Out)
{
    mfma_gemm_tile(Ch, Cl, WoTh, WoTl, Out, NQ_, D_, blockIdx.y * 128, blockIdx.x * 128);
}

// ---------------------------------------------------------------------------
// RoPE + split Q: Qw fp32 -> Qh/Ql bf16.
// ---------------------------------------------------------------------------
__global__ __launch_bounds__(128) void rope_split_q_kernel(
    const float* __restrict__ Qw, u16* __restrict__ Qh, u16* __restrict__ Ql)
{
    const int row = blockIdx.x;
    const int d = threadIdx.x;
    const int s = row & (S_ - 1);

    const float expo = (float)(2 * d) / (float)HD_;
    const float inv_freq = 1.0f / powf(10000.0f, expo);
    float sn, c;
    sincosf((float)s * inv_freq, &sn, &c);

    const float* qr = Qw + (size_t)row * NQ_;
    u16* qhr = Qh + (size_t)row * NQ_;
    u16* qlr = Ql + (size_t)row * NQ_;
#pragma unroll
    for (int h = 0; h < H_; ++h) {
        float x0 = qr[h * HD_ + d];
        float x1 = qr[h * HD_ + d + 128];
        float y0 = x0 * c - x1 * sn;
        float y1 = x1 * c + x0 * sn;
        u16 h0 = f2bf_rn(y0), h1 = f2bf_rn(y1);
        qhr[h * HD_ + d]       = h0;
        qhr[h * HD_ + d + 128] = h1;
        qlr[h * HD_ + d]       = f2bf_rn(y0 - bf2f(h0));
        qlr[h * HD_ + d + 128] = f2bf_rn(y1 - bf2f(h1));
    }
}

// RoPE + split K, written PRE-SWIZZLED for linear global_load_lds staging.
// Also zeroes the attn work-queue counter (block 0, thread 0).
__global__ __launch_bounds__(128) void rope_split_k_swz_kernel(
    const float* __restrict__ Kw, u16* __restrict__ Kh, u16* __restrict__ Kl,
    int* __restrict__ wq)
{
    if (blockIdx.x == 0 && threadIdx.x == 0) *wq = 0;

    const int row = blockIdx.x;
    const int d = threadIdx.x;
    const int s = row & (S_ - 1);
    const int xm = row & 7;

    const float expo = (float)(2 * d) / (float)HD_;
    const float inv_freq = 1.0f / powf(10000.0f, expo);
    float sn, c;
    sincosf((float)s * inv_freq, &sn, &c);

    const float* kr = Kw + (size_t)row * HD_;
    float x0 = kr[d], x1 = kr[d + 128];
    float y0 = x0 * c - x1 * sn;
    float y1 = x1 * c + x0 * sn;
    u16 h0 = f2bf_rn(y0), h1 = f2bf_rn(y1);

    const int o0 = (((d >> 3) ^ xm) << 3) | (d & 7);
    const int o1 = ((((d + 128) >> 3) ^ xm) << 3) | (d & 7);
    Kh[(size_t)row * HD_ + o0] = h0;
    Kh[(size_t)row * HD_ + o1] = h1;
    Kl[(size_t)row * HD_ + o0] = f2bf_rn(y0 - bf2f(h0));
    Kl[(size_t)row * HD_ + o1] = f2bf_rn(y1 - bf2f(h1));
}

// ---------------------------------------------------------------------------
// MFMA flash attention, split-bf16, causal, GQA(KV=1).
// Persistent: grid 256 (1 block/CU), work-queue of 512 (qt,bh) items,
// heavy-first (LPT).  LDS-bound throughput is per-CU, so 1 block/CU loses
// nothing; the queue fixes the makespan imbalance (occupancy 13% in R6).
// Inner loop = R6 2-phase async pipeline (verified).
// Epilogue writes context directly as bf16 hi/lo (Ch/Cl).
// ---------------------------------------------------------------------------
#define KVB_ 32
#define PBS_ 44
#define NITEM_ 512

__global__ __launch_bounds__(256, 2) void attn_mfma_kernel(
    const u16* __restrict__ Qh, const u16* __restrict__ Ql,
    const u16* __restrict__ Kh, const u16* __restrict__ Kl,
    const u16* __restrict__ VtH, const u16* __restrict__ VtL,
    u16* __restrict__ Ch, u16* __restrict__ Cl,
    int* __restrict__ wq)
{
    __shared__ u16 kvK[2 * 32 * 256];
    __shared__ u16 kvV[2 * 256 * 32];
    __shared__ u16 pb[2 * 64 * PBS_];
    __shared__ int s_item;

    const int tid = threadIdx.x;
    const int lane = tid & 63;
    const int w = tid >> 6;

    const int fr = lane & 15;
    const int kq = (lane >> 4);
    const int xm = fr & 7;

    // per-lane staging source coords (verified R6)
    const int k_hi = (lane >> 5);
    const int k_ch = lane & 31;
    const int v_dl = w * 64 + (lane >> 2);
    const int v_cc = (lane & 3) * 8;

    while (true) {
        __syncthreads();   // previous item's LDS reads done; protect s_item
        if (tid == 0) s_item = atomicAdd(wq, 1);
        __syncthreads();
        const int item = s_item;
        if (item >= NITEM_) break;

        const int qt = 31 - (item >> 4);   // heavy first
        const int bh = item & 15;
        const int b = bh >> 3, h = bh & 7;

        // ---- Q fragments (hi/lo) to registers ----
        short8v qfh[8], qfl[8];
        {
            const size_t qrow = (size_t)(b * S_ + qt * 64 + w * 16 + fr);
            const u16* ph = Qh + qrow * NQ_ + h * HD_ + kq * 8;
            const u16* pl = Ql + qrow * NQ_ + h * HD_ + kq * 8;
#pragma unroll
            for (int ks = 0; ks < 8; ++ks) {
                qfh[ks] = *(const short8v*)(ph + ks * 32);
                qfl[ks] = *(const short8v*)(pl + ks * 32);
            }
        }

        f32x4 oacc[16];
#pragma unroll
        for (int f = 0; f < 16; ++f) oacc[f] = (f32x4){0.f, 0.f, 0.f, 0.f};
        float m_i[4] = {-1e30f, -1e30f, -1e30f, -1e30f};
        float l_i[4] = {0.f, 0.f, 0.f, 0.f};

        const u16* ksrc[2] = {Kh + (size_t)b * S_ * HD_, Kl + (size_t)b * S_ * HD_};
        const u16* vsrc[2] = {VtH + (size_t)b * HD_ * S_, VtL + (size_t)b * HD_ * S_};

        const int nkt = (qt + 1) * 2;

#define STAGE_K(KT)                                                            \
        {                                                                      \
            _Pragma("unroll")                                                  \
            for (int c = 0; c < 2; ++c) {                                      \
                _Pragma("unroll")                                              \
                for (int t = 0; t < 4; ++t) {                                  \
                    const int rl = w * 8 + t * 2 + k_hi;                       \
                    gll16(ksrc[c] + (size_t)((KT) * KVB_ + rl) * HD_ + k_ch * 8, \
                          &kvK[c * 8192 + (w * 2048 + t * 512)]);              \
                }                                                              \
            }                                                                  \
        }

#define STAGE_V(KT)                                                            \
        {                                                                      \
            _Pragma("unroll")                                                  \
            for (int c = 0; c < 2; ++c) {                                      \
                _Pragma("unroll")                                              \
                for (int t = 0; t < 4; ++t) {                                  \
                    gll16(vsrc[c] + (size_t)(v_dl + t * 16) * S_ + (KT) * KVB_ + v_cc, \
                          &kvV[c * 8192 + (w * 2048 + t * 512)]);              \
                }                                                              \
            }                                                                  \
        }

        STAGE_K(0)
        STAGE_V(0)
        __syncthreads();

        for (int kt = 0; kt < nkt; ++kt) {
            const bool more = (kt + 1 < nkt);

            // ---- QK^T ----
            f32x4 s0 = (f32x4){0.f, 0.f, 0.f, 0.f};
            f32x4 s1 = (f32x4){0.f, 0.f, 0.f, 0.f};
#pragma unroll
            for (int ks = 0; ks < 8; ++ks) {
                const int ch = (ks * 4 + kq) ^ xm;
                short8v kh0 = *(const short8v*)&kvK[fr * 256 + ch * 8];
                short8v kh1 = *(const short8v*)&kvK[(16 + fr) * 256 + ch * 8];
                short8v kl0 = *(const short8v*)&kvK[8192 + fr * 256 + ch * 8];
                short8v kl1 = *(const short8v*)&kvK[8192 + (16 + fr) * 256 + ch * 8];
                s0 = __builtin_amdgcn_mfma_f32_16x16x32_bf16(qfh[ks], kh0, s0, 0, 0, 0);
                s1 = __builtin_amdgcn_mfma_f32_16x16x32_bf16(qfh[ks], kh1, s1, 0, 0, 0);
                s0 = __builtin_amdgcn_mfma_f32_16x16x32_bf16(qfh[ks], kl0, s0, 0, 0, 0);
                s1 = __builtin_amdgcn_mfma_f32_16x16x32_bf16(qfh[ks], kl1, s1, 0, 0, 0);
                s0 = __builtin_amdgcn_mfma_f32_16x16x32_bf16(qfl[ks], kh0, s0, 0, 0, 0);
                s1 = __builtin_amdgcn_mfma_f32_16x16x32_bf16(qfl[ks], kh1, s1, 0, 0, 0);
            }

            // ---- online softmax, cheap defer-predicate ----
            const int qglob = qt * 64 + w * 16 + kq * 4;
            const int kg = kt * KVB_ + fr;
            float x0v[4], x1v[4], mxl[4];
            bool needl = false;
#pragma unroll
            for (int r = 0; r < 4; ++r) {
                float x0 = s0[r] * 0.0625f;
                float x1 = s1[r] * 0.0625f;
                if (kg > qglob + r)      x0 = -1e30f;
                if (kg + 16 > qglob + r) x1 = -1e30f;
                x0v[r] = x0; x1v[r] = x1;
                mxl[r] = fmaxf(x0, x1);
                needl = needl || (mxl[r] > m_i[r] + 8.0f);
            }
            if (__any((int)needl)) {
#pragma unroll
                for (int r = 0; r < 4; ++r) {
                    float mx = mxl[r];
#pragma unroll
                    for (int off = 1; off < 16; off <<= 1)
                        mx = fmaxf(mx, __shfl_xor(mx, off, 64));
                    const float mnew = fmaxf(m_i[r], mx);
                    const float alpha = __expf(m_i[r] - mnew);
                    l_i[r] *= alpha;
                    m_i[r] = mnew;
#pragma unroll
                    for (int f = 0; f < 16; ++f) oacc[f][r] *= alpha;
                }
            }
#pragma unroll
            for (int r = 0; r < 4; ++r) {
                const float p0 = __expf(x0v[r] - m_i[r]);
                const float p1 = __expf(x1v[r] - m_i[r]);
                float ps = p0 + p1;
#pragma unroll
                for (int off = 1; off < 16; off <<= 1)
                    ps += __shfl_xor(ps, off, 64);
                l_i[r] += ps;

                const int prow = (w * 16 + kq * 4 + r) * PBS_;
                u16 h0 = f2bf_rn(p0), h1 = f2bf_rn(p1);
                pb[prow + fr]                    = h0;
                pb[prow + 16 + fr]               = h1;
                pb[64 * PBS_ + prow + fr]        = f2bf_rn(p0 - bf2f(h0));
                pb[64 * PBS_ + prow + 16 + fr]   = f2bf_rn(p1 - bf2f(h1));
            }
            __syncthreads();   // barA: K free, P visible, V(kt) drained

            if (more) STAGE_K(kt + 1)

            // ---- PV ----
            {
                short8v pah = *(const short8v*)&pb[(w * 16 + fr) * PBS_ + kq * 8];
                short8v pal = *(const short8v*)&pb[64 * PBS_ + (w * 16 + fr) * PBS_ + kq * 8];
#pragma unroll
                for (int f = 0; f < 16; ++f) {
                    const int vrow = (f * 16 + fr) * 32 + kq * 8;
                    short8v vh = *(const short8v*)&kvV[vrow];
                    short8v vl = *(const short8v*)&kvV[8192 + vrow];
                    oacc[f] = __builtin_amdgcn_mfma_f32_16x16x32_bf16(pah, vh, oacc[f], 0, 0, 0);
                    oacc[f] = __builtin_amdgcn_mfma_f32_16x16x32_bf16(pal, vh, oacc[f], 0, 0, 0);
                    oacc[f] = __builtin_amdgcn_mfma_f32_16x16x32_bf16(pah, vl, oacc[f], 0, 0, 0);
                }
            }
            if (more) {
                __syncthreads();   // barB: V free, K(kt+1) drained
                STAGE_V(kt + 1)
            }
        }

        // ---- epilogue: context as bf16 hi/lo directly ----
        {
            const size_t obase = (size_t)(b * S_ + qt * 64 + w * 16 + kq * 4) * NQ_ + h * HD_ + fr;
            u16* ohr = Ch + obase;
            u16* olr = Cl + obase;
#pragma unroll
            for (int r = 0; r < 4; ++r) {
                const float inv_l = 1.0f / l_i[r];
#pragma unroll
                for (int f = 0; f < 16; ++f) {
                    const float v = oacc[f][r] * inv_l;
                    const u16 hh = f2bf_rn(v);
                    ohr[(size_t)r * NQ_ + f * 16] = hh;
                    olr[(size_t)r * NQ_ + f * 16] = f2bf_rn(v - bf2f(hh));
                }
            }
        }
#undef STAGE_K
#undef STAGE_V
    }
}

// ---------------------------------------------------------------------------
extern "C" void kernel_launch(void* const* d_in, const int* in_sizes, int n_in,
                              void* d_out, int out_size, void* d_ws, size_t ws_size,
                              hipStream_t stream)
{
    (void)in_sizes; (void)n_in; (void)out_size; (void)ws_size;

    const float* hidden = (const float*)d_in[0];
    const float* Wq = (const float*)d_in[3];
    const float* Wk = (const float*)d_in[4];
    const float* Wv = (const float*)d_in[5];
    const float* Wo = (const float*)d_in[6];
    float* out = (float*)d_out;

    char* ws = (char*)d_ws;
    float* Qw = (float*)(ws + 0);
    u16* Kh2 = (u16*)(ws + 0);               // Qw region reused after rope_split_q
    u16* Kl2 = (u16*)(ws + 2097152u);
    u16* VtH = (u16*)(ws + 4194304u);
    u16* VtL = (u16*)(ws + 6291456u);
    int* wq  = (int*)(ws + 8388608u);        // attn work-queue counter
    float* Kw = (float*)(ws + 33554432u);
    float* Vw = (float*)(ws + 37748736u);
    u16* Ch2 = (u16*)(ws + 41943040u);       // context hi/lo (old Cw region)
    u16* Cl2 = (u16*)(ws + 58720256u);
    u16* Ah  = (u16*)(ws + 75497472u);
    u16* Al  = (u16*)(ws + 92274688u);
    u16* WqTh = (u16*)(ws + 109051904u);
    u16* WqTl = (u16*)(ws + 117440512u);
    u16* WkTh = (u16*)(ws + 125829120u);
    u16* WkTl = (u16*)(ws + 126877696u);
    u16* WvTh = (u16*)(ws + 127926272u);
    u16* WvTl = (u16*)(ws + 128974848u);
    u16* WoTh = WqTh;
    u16* WoTl = WqTl;
    u16* Qhb = Ah;
    u16* Qlb = Al;

    split_kernel<<<dim3((M_ * D_) / (256 * 8)), dim3(256), 0, stream>>>(hidden, Ah, Al);

    tsplit_kernel<<<dim3(D_ / 64, NQ_ / 64),  dim3(256), 0, stream>>>(Wq, WqTh, WqTl, D_, NQ_);
    tsplit_kernel<<<dim3(D_ / 64, NKV_ / 64), dim3(256), 0, stream>>>(Wk, WkTh, WkTl, D_, NKV_);
    tsplit_kernel<<<dim3(D_ / 64, NKV_ / 64), dim3(256), 0, stream>>>(Wv, WvTh, WvTl, D_, NKV_);

    qkv_mfma_kernel<<<dim3(20, M_ / 128), dim3(256), 0, stream>>>(
        Ah, Al, WqTh, WqTl, WkTh, WkTl, WvTh, WvTl, Qw, Kw, Vw);

    rope_split_q_kernel<<<dim3(M_), dim3(128), 0, stream>>>(Qw, Qhb, Qlb);
    rope_split_k_swz_kernel<<<dim3(M_), dim3(128), 0, stream>>>(Kw, Kh2, Kl2, wq);

    tsplit_kernel<<<dim3(S_ / 64, NKV_ / 64), dim3(256), 0, stream>>>(
        Vw, VtH, VtL, S_, NKV_);
    tsplit_kernel<<<dim3(S_ / 64, NKV_ / 64), dim3(256), 0, stream>>>(
        Vw + (size_t)S_ * NKV_, VtH + (size_t)HD_ * S_, VtL + (size_t)HD_ * S_, S_, NKV_);

    attn_mfma_kernel<<<dim3(256), dim3(256), 0, stream>>>(
        Qhb, Qlb, Kh2, Kl2, VtH, VtL, Ch2, Cl2, wq);

    tsplit_kernel<<<dim3(NQ_ / 64, D_ / 64), dim3(256), 0, stream>>>(Wo, WoTh, WoTl, NQ_, D_);

    out_mfma_kernel<<<dim3(D_ / 128, M_ / 128), dim3(256), 0, stream>>>(
        Ch2, Cl2, WoTh, WoTl, out);
}